// Round 1
// baseline (152.826 us; speedup 1.0000x reference)
//
#include <hip/hip_runtime.h>
#include <math.h>

// ---------------------------------------------------------------------------
// Difflogic network, collapsed form:
//   per neuron: out = c0 + c1*p + c2*q + c3*p*q,  p = A·x, q = B·x
//   A,B = softmax(sel), (c0..c3) = softmax(gate_logits) · gate-coef table
//
// R8 -> R9: FUSE coeff derivation into the net kernel; drop d_ws entirely.
// Evidence: rocprof top-5 dispatches are all 256 MiB fillBufferAligned
// (42-45us each) = harness poisoning the WORKSPACE; net_kernel is not even
// in the top-5 (<42us), and its roofline is ~7us (41.9MB @ 6.3TB/s).
// The 107us is dominated by ws-poison + the <<<1,64>>> coeff kernel's
// serialization bubble, not by our math.
// Structure: wave 0 of each block runs R6's one-task-per-lane coeff code
// (arrays fully unrolled -> registers, no R7-style scratch spill) into
// 1.15KB LDS, __syncthreads, then the unchanged net body reads cf[] via
// uniform-address (broadcast, conflict-free) LDS loads.
// NOTE: coeff+sync must be reached by ALL threads -> tail guard moved to
// AFTER the barrier (no early return).
//
// cf layout (floats):
//   A1:   0 (72)   B1:  72 (72)   C1: 144 (32)
//   A2: 176 (32)   B2: 208 (32)   C2: 240 (16)
//   A3: 256 ( 8)   B3: 264 ( 8)   C3: 272 ( 8)
//   A4: 280 ( 2)   B4: 282 ( 2)   C4: 284 ( 4)   total 288 floats = 1152 B
// ---------------------------------------------------------------------------

#define THREADS 256
#define SPT 4                          // consecutive samples per thread
#define B_PER_BLOCK (THREADS * SPT)

template <int D>
__device__ __forceinline__ void softmax_row(const float* __restrict__ src,
                                            float* __restrict__ dst) {
    float e[D];
    float m = src[0];
    #pragma unroll
    for (int i = 1; i < D; ++i) m = fmaxf(m, src[i]);
    float s = 0.f;
    #pragma unroll
    for (int i = 0; i < D; ++i) { e[i] = __expf(src[i] - m); s += e[i]; }
    float inv = 1.f / s;
    #pragma unroll
    for (int i = 0; i < D; ++i) dst[i] = e[i] * inv;
}

__device__ __forceinline__ void gate_fold(const float* __restrict__ g,
                                          float* __restrict__ C) {
    const float k0[16]  = {0,0,0,0, 0,0,0,0, 1, 1, 1, 1, 1, 1, 1, 1};
    const float kp[16]  = {0,0,1,1, 0,0,1,1,-1,-1, 0, 0,-1,-1, 0, 0};
    const float kq[16]  = {0,0,0,0, 1,1,1,1,-1,-1,-1,-1, 0, 0, 0, 0};
    const float kpq[16] = {0,1,-1,0,-1,0,-2,-1, 1, 2, 0, 1, 0, 1,-1, 0};
    float w[16];
    float m = g[0];
    #pragma unroll
    for (int i = 1; i < 16; ++i) m = fmaxf(m, g[i]);
    float s = 0.f;
    #pragma unroll
    for (int i = 0; i < 16; ++i) { w[i] = __expf(g[i] - m); s += w[i]; }
    float inv = 1.f / s;
    float c0 = 0, c1 = 0, c2 = 0, c3 = 0;
    #pragma unroll
    for (int i = 0; i < 16; ++i) {
        float wi = w[i] * inv;
        c0 = fmaf(wi, k0[i], c0); c1 = fmaf(wi, kp[i], c1);
        c2 = fmaf(wi, kq[i], c2); c3 = fmaf(wi, kpq[i], c3);
    }
    C[0] = c0; C[1] = c1; C[2] = c2; C[3] = c3;
}

__global__ __launch_bounds__(THREADS, 4) void fused_kernel(
        const float* __restrict__ x,
        const float* __restrict__ sa1, const float* __restrict__ sb1, const float* __restrict__ g1,
        const float* __restrict__ sa2, const float* __restrict__ sb2, const float* __restrict__ g2,
        const float* __restrict__ sa3, const float* __restrict__ sb3, const float* __restrict__ g3,
        const float* __restrict__ sa4, const float* __restrict__ sb4, const float* __restrict__ g4,
        float* __restrict__ out, int nB) {
    __shared__ float cf[288];

    // ---- Phase 0: wave 0 derives all 288 coefficients into LDS.
    //      One task per lane (R6 structure): local arrays fully unrolled
    //      with constant indices -> VGPRs, no scratch even under divergence.
    {
        const int t = threadIdx.x;
        if (t < 15) {                     // softmax of sel_a rows
            int r = t;
            if      (r < 8)  softmax_row<9>(sa1 + r * 9,        cf + r * 9);
            else if (r < 12) softmax_row<8>(sa2 + (r - 8) * 8,  cf + 176 + (r - 8) * 8);
            else if (r < 14) softmax_row<4>(sa3 + (r - 12) * 4, cf + 256 + (r - 12) * 4);
            else             softmax_row<2>(sa4,                cf + 280);
        } else if (t >= 16 && t < 31) {   // softmax of sel_b rows
            int r = t - 16;
            if      (r < 8)  softmax_row<9>(sb1 + r * 9,        cf + 72 + r * 9);
            else if (r < 12) softmax_row<8>(sb2 + (r - 8) * 8,  cf + 208 + (r - 8) * 8);
            else if (r < 14) softmax_row<4>(sb3 + (r - 12) * 4, cf + 264 + (r - 12) * 4);
            else             softmax_row<2>(sb4,                cf + 282);
        } else if (t >= 32 && t < 47) {   // gate-logit folds
            int r = t - 32;
            if      (r < 8)  gate_fold(g1 + r * 16,        cf + 144 + r * 4);
            else if (r < 12) gate_fold(g2 + (r - 8) * 16,  cf + 240 + (r - 8) * 4);
            else if (r < 14) gate_fold(g3 + (r - 12) * 16, cf + 272 + (r - 12) * 4);
            else             gate_fold(g4,                 cf + 284);
        }
    }
    __syncthreads();   // ALL threads reach this (tail guard is below)

    const int T  = blockIdx.x * THREADS + threadIdx.x;  // sample-group id
    const int b0 = T * SPT;
    if (b0 >= nB) return;

    // ---- load 4 consecutive samples = 36 contiguous floats = 9 dwordx4 ----
    float v[SPT][9];
    if (b0 + SPT <= nB) {
        const float4* __restrict__ x4 = (const float4*)x;
        float4 r[9];
        #pragma unroll
        for (int k = 0; k < 9; ++k) r[k] = x4[(long)T * 9 + k];
        const float* rf = (const float*)r;   // constant-index after unroll -> VGPRs
        #pragma unroll
        for (int s = 0; s < SPT; ++s)
            #pragma unroll
            for (int i = 0; i < 9; ++i) v[s][i] = rf[s * 9 + i];
    } else {
        #pragma unroll
        for (int s = 0; s < SPT; ++s)
            #pragma unroll
            for (int i = 0; i < 9; ++i) {
                int b = b0 + s;
                v[s][i] = (b < nB) ? x[(long)b * 9 + i] : 0.f;
            }
    }

    // ---- Layer 1: 9 -> 8. cf[] = LDS, uniform address -> broadcast reads.
    float h1[SPT][8];
    #pragma unroll
    for (int j = 0; j < 8; ++j) {
        #pragma unroll
        for (int s = 0; s < SPT; ++s) {
            float p = 0.f, q = 0.f;
            #pragma unroll
            for (int i = 0; i < 9; ++i) {
                p = fmaf(v[s][i], cf[     j * 9 + i], p);
                q = fmaf(v[s][i], cf[72 + j * 9 + i], q);
            }
            h1[s][j] = fmaf(cf[144 + j*4 + 3], p * q,
                       fmaf(cf[144 + j*4 + 2], q,
                       fmaf(cf[144 + j*4 + 1], p, cf[144 + j*4 + 0])));
        }
    }
    // ---- Layer 2: 8 -> 4 ----
    float h2[SPT][4];
    #pragma unroll
    for (int j = 0; j < 4; ++j) {
        #pragma unroll
        for (int s = 0; s < SPT; ++s) {
            float p = 0.f, q = 0.f;
            #pragma unroll
            for (int i = 0; i < 8; ++i) {
                p = fmaf(h1[s][i], cf[176 + j * 8 + i], p);
                q = fmaf(h1[s][i], cf[208 + j * 8 + i], q);
            }
            h2[s][j] = fmaf(cf[240 + j*4 + 3], p * q,
                       fmaf(cf[240 + j*4 + 2], q,
                       fmaf(cf[240 + j*4 + 1], p, cf[240 + j*4 + 0])));
        }
    }
    // ---- Layer 3: 4 -> 2 ----
    float h3[SPT][2];
    #pragma unroll
    for (int j = 0; j < 2; ++j) {
        #pragma unroll
        for (int s = 0; s < SPT; ++s) {
            float p = 0.f, q = 0.f;
            #pragma unroll
            for (int i = 0; i < 4; ++i) {
                p = fmaf(h2[s][i], cf[256 + j * 4 + i], p);
                q = fmaf(h2[s][i], cf[264 + j * 4 + i], q);
            }
            h3[s][j] = fmaf(cf[272 + j*4 + 3], p * q,
                       fmaf(cf[272 + j*4 + 2], q,
                       fmaf(cf[272 + j*4 + 1], p, cf[272 + j*4 + 0])));
        }
    }
    // ---- Layer 4: 2 -> 1, one float4 store per thread ----
    float o[SPT];
    #pragma unroll
    for (int s = 0; s < SPT; ++s) {
        float p = fmaf(h3[s][0], cf[280], h3[s][1] * cf[281]);
        float q = fmaf(h3[s][0], cf[282], h3[s][1] * cf[283]);
        o[s] = fmaf(cf[287], p * q,
               fmaf(cf[286], q,
               fmaf(cf[285], p, cf[284])));
    }
    if (b0 + SPT <= nB) {
        float4* __restrict__ out4 = (float4*)out;
        float4 w; w.x = o[0]; w.y = o[1]; w.z = o[2]; w.w = o[3];
        out4[T] = w;
    } else {
        #pragma unroll
        for (int s = 0; s < SPT; ++s)
            if (b0 + s < nB) out[b0 + s] = o[s];
    }
}

extern "C" void kernel_launch(void* const* d_in, const int* in_sizes, int n_in,
                              void* d_out, int out_size, void* d_ws, size_t ws_size,
                              hipStream_t stream) {
    const float* x   = (const float*)d_in[0];
    const float* sa1 = (const float*)d_in[1];
    const float* sb1 = (const float*)d_in[2];
    const float* g1  = (const float*)d_in[3];
    const float* sa2 = (const float*)d_in[4];
    const float* sb2 = (const float*)d_in[5];
    const float* g2  = (const float*)d_in[6];
    const float* sa3 = (const float*)d_in[7];
    const float* sb3 = (const float*)d_in[8];
    const float* g3  = (const float*)d_in[9];
    const float* sa4 = (const float*)d_in[10];
    const float* sb4 = (const float*)d_in[11];
    const float* g4  = (const float*)d_in[12];
    (void)d_ws; (void)ws_size;                // deliberately unused (see header)
    const int nB = in_sizes[0] / 9;

    const int grid = (nB + B_PER_BLOCK - 1) / B_PER_BLOCK;
    fused_kernel<<<grid, THREADS, 0, stream>>>(x,
                                               sa1, sb1, g1, sa2, sb2, g2,
                                               sa3, sb3, g3, sa4, sb4, g4,
                                               (float*)d_out, nB);
}

// Round 3
// 133.894 us; speedup vs baseline: 1.1414x; 1.1414x over previous
//
#include <hip/hip_runtime.h>
#include <math.h>

// ---------------------------------------------------------------------------
// Difflogic network, collapsed form:
//   per neuron: out = c0 + c1*p + c2*q + c3*p*q,  p = A·x, q = B·x
//   A,B = softmax(sel), (c0..c3) = softmax(gate_logits) · gate-coef table
//
// R10 -> R11: compile fix only (__builtin_nontemporal_store rejects
// HIP_vector_type float4 -> plain store; out is 4MB, negligible either way).
// R10 theory stands:
//  1. amdgpu_waves_per_eu(4,4): pin allocator to 128-VGPR budget; stops the
//     occupancy heuristic from spilling to reach 8 waves/EU (R9: VGPR=64,
//     WRITE_SIZE=119MiB of scratch).
//  2. Coeff phase one-OUTPUT-per-thread (288 straight-line tasks, no private
//     arrays, no divergent calls) -> ~0 register pressure before barrier.
//  3. Explicit .x/.y/.z/.w unpack of float4 loads (no pointer-cast aliasing).
//  4. cf[] padded to 16B rows; coeffs read as uniform-address ds_read_b128
//     broadcasts (~84/thread instead of ~280 b32).
//
// cf LDS layout (floats, 16B-aligned rows; float4 index in brackets):
//   A1:   0 (8 rows x 12, 9 used)  [f4   0..23]
//   B1:  96 (8 x 12)               [f4  24..47]
//   C1: 192 (8 x 4)                [f4  48..55]
//   A2: 224 (4 x 8)                [f4  56..63]
//   B2: 256 (4 x 8)                [f4  64..71]
//   C2: 288 (4 x 4)                [f4  72..75]
//   A3: 304 (2 x 4)                [f4  76..77]
//   B3: 312 (2 x 4)                [f4  78..79]
//   C3: 320 (2 x 4)                [f4  80..81]
//   A4: 328 (2)  B4: 330 (2)       [f4  82    ]
//   C4: 332 (4)                    [f4  83    ]   total 336 floats = 1344 B
// ---------------------------------------------------------------------------

#define THREADS 256
#define SPT 4                          // consecutive samples per thread
#define B_PER_BLOCK (THREADS * SPT)

// One softmax OUTPUT element: thread computes dst = exp(row[i]-m)/sum.
// Small dynamic loops (D<=9), no local arrays -> no scratch, ~15 VGPRs.
__device__ __forceinline__ void sm_elem(int e,
        const float* __restrict__ p1, const float* __restrict__ p2,
        const float* __restrict__ p3, const float* __restrict__ p4,
        int o1, int o2, int o3, int o4, float* __restrict__ cf) {
    const float* row; int D, i, dst;
    if (e < 72)       { int r = e / 9;            i = e - r * 9; row = p1 + r * 9; D = 9; dst = o1 + r * 12 + i; }
    else if (e < 104) { int u = e - 72,  r = u >> 3; i = u & 7;  row = p2 + r * 8; D = 8; dst = o2 + u; }
    else if (e < 112) { int u = e - 104, r = u >> 2; i = u & 3;  row = p3 + r * 4; D = 4; dst = o3 + u; }
    else              { int u = e - 112;             i = u;      row = p4;         D = 2; dst = o4 + u; }
    float m = -1e30f;
    for (int k = 0; k < D; ++k) m = fmaxf(m, row[k]);
    float s = 0.f;
    for (int k = 0; k < D; ++k) s += __expf(row[k] - m);
    cf[dst] = __expf(row[i] - m) / s;
}

// One gate coefficient: c = (softmax(g) . ktab[k]) for k in {0..3}.
// ktab entries are compile-time per i; runtime-k select is 3 cndmasks.
__device__ __forceinline__ void gate_elem(int c,
        const float* __restrict__ g1, const float* __restrict__ g2,
        const float* __restrict__ g3, const float* __restrict__ g4,
        float* __restrict__ cf) {
    const int n = c >> 2, k = c & 3;
    const float* g; int dst;
    if (n < 8)       { g = g1 + n * 16;        dst = 192 + n * 4 + k; }
    else if (n < 12) { g = g2 + (n - 8) * 16;  dst = 288 + (n - 8) * 4 + k; }
    else if (n < 14) { g = g3 + (n - 12) * 16; dst = 320 + (n - 12) * 4 + k; }
    else             { g = g4;                 dst = 332 + k; }
    const float k0[16]  = {0,0,0,0, 0,0,0,0, 1, 1, 1, 1, 1, 1, 1, 1};
    const float kp[16]  = {0,0,1,1, 0,0,1,1,-1,-1, 0, 0,-1,-1, 0, 0};
    const float kq[16]  = {0,0,0,0, 1,1,1,1,-1,-1,-1,-1, 0, 0, 0, 0};
    const float kpq[16] = {0,1,-1,0,-1,0,-2,-1, 1, 2, 0, 1, 0, 1,-1, 0};
    float m = g[0];
    #pragma unroll
    for (int i = 1; i < 16; ++i) m = fmaxf(m, g[i]);
    float s = 0.f, acc = 0.f;
    #pragma unroll
    for (int i = 0; i < 16; ++i) {
        float w = __expf(g[i] - m);
        s += w;
        float kv = (k == 0) ? k0[i] : (k == 1) ? kp[i] : (k == 2) ? kq[i] : kpq[i];
        acc = fmaf(w, kv, acc);
    }
    cf[dst] = acc / s;
}

__global__ __launch_bounds__(THREADS)
__attribute__((amdgpu_waves_per_eu(4, 4)))   // pin: 4 waves/EU exactly -> 128-VGPR cap, no heuristic spill
void fused_kernel(
        const float* __restrict__ x,
        const float* __restrict__ sa1, const float* __restrict__ sb1, const float* __restrict__ g1,
        const float* __restrict__ sa2, const float* __restrict__ sb2, const float* __restrict__ g2,
        const float* __restrict__ sa3, const float* __restrict__ sb3, const float* __restrict__ g3,
        const float* __restrict__ sa4, const float* __restrict__ sb4, const float* __restrict__ g4,
        float* __restrict__ out, int nB) {
    __shared__ __align__(16) float cf[336];

    // ---- Phase 0: 288 coefficient outputs, one per thread (t and t+256). ----
    for (int t = threadIdx.x; t < 288; t += THREADS) {
        if (t < 114)      sm_elem(t,       sa1, sa2, sa3, sa4,   0, 224, 304, 328, cf);
        else if (t < 228) sm_elem(t - 114, sb1, sb2, sb3, sb4,  96, 256, 312, 330, cf);
        else              gate_elem(t - 228, g1, g2, g3, g4, cf);
    }
    __syncthreads();   // ALL threads reach this (tail guard below)

    const int T  = blockIdx.x * THREADS + threadIdx.x;  // sample-group id
    const int b0 = T * SPT;
    if (b0 >= nB) return;

    const float4* __restrict__ cf4 = (const float4*)cf;

    // ---- load 4 consecutive samples = 36 contiguous floats = 9 dwordx4 ----
    float v[SPT * 9];
    if (b0 + SPT <= nB) {
        const float4* __restrict__ x4 = (const float4*)x;
        float4 r[9];
        #pragma unroll
        for (int k = 0; k < 9; ++k) r[k] = x4[(long)T * 9 + k];
        #pragma unroll
        for (int k = 0; k < 9; ++k) {   // explicit unpack: constant indices -> VGPRs
            v[4 * k + 0] = r[k].x; v[4 * k + 1] = r[k].y;
            v[4 * k + 2] = r[k].z; v[4 * k + 3] = r[k].w;
        }
    } else {
        #pragma unroll
        for (int s = 0; s < SPT; ++s)
            #pragma unroll
            for (int i = 0; i < 9; ++i) {
                int b = b0 + s;
                v[s * 9 + i] = (b < nB) ? x[(long)b * 9 + i] : 0.f;
            }
    }

    // ---- Layer 1: 9 -> 8.  Coeffs via b128 broadcast reads. ----
    float h1[SPT][8];
    #pragma unroll
    for (int j = 0; j < 8; ++j) {
        float4 A0 = cf4[j * 3 + 0], A1 = cf4[j * 3 + 1], A2 = cf4[j * 3 + 2];
        float4 B0 = cf4[24 + j * 3 + 0], B1v = cf4[24 + j * 3 + 1], B2v = cf4[24 + j * 3 + 2];
        float4 C  = cf4[48 + j];
        const float a[9] = {A0.x, A0.y, A0.z, A0.w, A1.x, A1.y, A1.z, A1.w, A2.x};
        const float b[9] = {B0.x, B0.y, B0.z, B0.w, B1v.x, B1v.y, B1v.z, B1v.w, B2v.x};
        #pragma unroll
        for (int s = 0; s < SPT; ++s) {
            float p = 0.f, q = 0.f;
            #pragma unroll
            for (int i = 0; i < 9; ++i) {
                p = fmaf(v[s * 9 + i], a[i], p);
                q = fmaf(v[s * 9 + i], b[i], q);
            }
            h1[s][j] = fmaf(C.w, p * q, fmaf(C.z, q, fmaf(C.y, p, C.x)));
        }
    }
    // ---- Layer 2: 8 -> 4 ----
    float h2[SPT][4];
    #pragma unroll
    for (int j = 0; j < 4; ++j) {
        float4 A0 = cf4[56 + j * 2 + 0], A1 = cf4[56 + j * 2 + 1];
        float4 B0 = cf4[64 + j * 2 + 0], B1v = cf4[64 + j * 2 + 1];
        float4 C  = cf4[72 + j];
        const float a[8] = {A0.x, A0.y, A0.z, A0.w, A1.x, A1.y, A1.z, A1.w};
        const float b[8] = {B0.x, B0.y, B0.z, B0.w, B1v.x, B1v.y, B1v.z, B1v.w};
        #pragma unroll
        for (int s = 0; s < SPT; ++s) {
            float p = 0.f, q = 0.f;
            #pragma unroll
            for (int i = 0; i < 8; ++i) {
                p = fmaf(h1[s][i], a[i], p);
                q = fmaf(h1[s][i], b[i], q);
            }
            h2[s][j] = fmaf(C.w, p * q, fmaf(C.z, q, fmaf(C.y, p, C.x)));
        }
    }
    // ---- Layer 3: 4 -> 2 ----
    float h3[SPT][2];
    #pragma unroll
    for (int j = 0; j < 2; ++j) {
        float4 A = cf4[76 + j], B = cf4[78 + j], C = cf4[80 + j];
        #pragma unroll
        for (int s = 0; s < SPT; ++s) {
            float p = fmaf(h2[s][0], A.x, fmaf(h2[s][1], A.y,
                      fmaf(h2[s][2], A.z, h2[s][3] * A.w)));
            float q = fmaf(h2[s][0], B.x, fmaf(h2[s][1], B.y,
                      fmaf(h2[s][2], B.z, h2[s][3] * B.w)));
            h3[s][j] = fmaf(C.w, p * q, fmaf(C.z, q, fmaf(C.y, p, C.x)));
        }
    }
    // ---- Layer 4: 2 -> 1, one float4 store per thread ----
    {
        float4 AB = cf4[82];   // A4 = .x.y, B4 = .z.w
        float4 C  = cf4[83];
        float o[SPT];
        #pragma unroll
        for (int s = 0; s < SPT; ++s) {
            float p = fmaf(h3[s][0], AB.x, h3[s][1] * AB.y);
            float q = fmaf(h3[s][0], AB.z, h3[s][1] * AB.w);
            o[s] = fmaf(C.w, p * q, fmaf(C.z, q, fmaf(C.y, p, C.x)));
        }
        if (b0 + SPT <= nB) {
            float4* __restrict__ out4 = (float4*)out;
            float4 w; w.x = o[0]; w.y = o[1]; w.z = o[2]; w.w = o[3];
            out4[T] = w;
        } else {
            #pragma unroll
            for (int s = 0; s < SPT; ++s)
                if (b0 + s < nB) out[b0 + s] = o[s];
        }
    }
}

extern "C" void kernel_launch(void* const* d_in, const int* in_sizes, int n_in,
                              void* d_out, int out_size, void* d_ws, size_t ws_size,
                              hipStream_t stream) {
    const float* x   = (const float*)d_in[0];
    const float* sa1 = (const float*)d_in[1];
    const float* sb1 = (const float*)d_in[2];
    const float* g1  = (const float*)d_in[3];
    const float* sa2 = (const float*)d_in[4];
    const float* sb2 = (const float*)d_in[5];
    const float* g2  = (const float*)d_in[6];
    const float* sa3 = (const float*)d_in[7];
    const float* sb3 = (const float*)d_in[8];
    const float* g3  = (const float*)d_in[9];
    const float* sa4 = (const float*)d_in[10];
    const float* sb4 = (const float*)d_in[11];
    const float* g4  = (const float*)d_in[12];
    (void)d_ws; (void)ws_size;                // deliberately unused
    const int nB = in_sizes[0] / 9;

    const int grid = (nB + B_PER_BLOCK - 1) / B_PER_BLOCK;
    fused_kernel<<<grid, THREADS, 0, stream>>>(x,
                                               sa1, sb1, g1, sa2, sb2, g2,
                                               sa3, sb3, g3, sa4, sb4, g4,
                                               (float*)d_out, nB);
}

// Round 4
// 110.173 us; speedup vs baseline: 1.3871x; 1.2153x over previous
//
#include <hip/hip_runtime.h>
#include <math.h>

// ---------------------------------------------------------------------------
// Difflogic network, collapsed form:
//   per neuron: out = c0 + c1*p + c2*q + c3*p*q,  p = A·x, q = B·x
//   A,B = softmax(sel), (c0..c3) = softmax(gate_logits) · gate-coef table
//
// R11 -> R12: stop fighting the register allocator; make pressure tiny.
// Evidence: R11 VGPR=64 + WRITE_SIZE 74MB = 72 floats/thread spilled
// (= v[36]+h1[32]); launch_bounds(256,4) and waves_per_eu(4,4) both failed
// to stop the 8-wave/EU spill on the SPT=4 fused shape. Also: the 2x43us
// 256MiB poison-fills happen whether or not we touch d_ws (R0 and R11 both
// show the same ~86us floor) -> using d_ws is FREE.
// Structure:
//   1. coeff_kernel <<<1,64>>> (R5/R8-proven, arrays promote to registers)
//      writes 288 coeff floats to d_ws.
//   2. net_kernel, SPT=1: block stages its 2304-float x-chunk to LDS with
//      coalesced float4 loads; each thread computes ONE sample.
//      Live state ~30 VGPR; launch_bounds(256,8) pins the 64-VGPR budget
//      which the body now FITS (8 waves/EU, 32 waves/CU, 2x R8 occupancy).
//      Coeffs via uniform cf pointer + constant offsets -> s_load -> SGPR
//      operands in v_fma: zero VGPR cost for all 288 coefficients.
//      LDS read xs[tid*9+i]: stride 9 (odd) -> 2 lanes/bank = conflict-free.
//
// ws layout (floats):
//   A1:   0 (72)   B1:  72 (72)   C1: 144 (32)
//   A2: 176 (32)   B2: 208 (32)   C2: 240 (16)
//   A3: 256 ( 8)   B3: 264 ( 8)   C3: 272 ( 8)
//   A4: 280 ( 2)   B4: 282 ( 2)   C4: 284 ( 4)   total 288 floats = 1152 B
// ---------------------------------------------------------------------------

#define THREADS 256

template <int D>
__device__ __forceinline__ void softmax_row(const float* __restrict__ src,
                                            float* __restrict__ dst) {
    float e[D];
    float m = src[0];
    #pragma unroll
    for (int i = 1; i < D; ++i) m = fmaxf(m, src[i]);
    float s = 0.f;
    #pragma unroll
    for (int i = 0; i < D; ++i) { e[i] = __expf(src[i] - m); s += e[i]; }
    float inv = 1.f / s;
    #pragma unroll
    for (int i = 0; i < D; ++i) dst[i] = e[i] * inv;
}

__device__ __forceinline__ void gate_fold(const float* __restrict__ g,
                                          float* __restrict__ C) {
    const float k0[16]  = {0,0,0,0, 0,0,0,0, 1, 1, 1, 1, 1, 1, 1, 1};
    const float kp[16]  = {0,0,1,1, 0,0,1,1,-1,-1, 0, 0,-1,-1, 0, 0};
    const float kq[16]  = {0,0,0,0, 1,1,1,1,-1,-1,-1,-1, 0, 0, 0, 0};
    const float kpq[16] = {0,1,-1,0,-1,0,-2,-1, 1, 2, 0, 1, 0, 1,-1, 0};
    float w[16];
    float m = g[0];
    #pragma unroll
    for (int i = 1; i < 16; ++i) m = fmaxf(m, g[i]);
    float s = 0.f;
    #pragma unroll
    for (int i = 0; i < 16; ++i) { w[i] = __expf(g[i] - m); s += w[i]; }
    float inv = 1.f / s;
    float c0 = 0, c1 = 0, c2 = 0, c3 = 0;
    #pragma unroll
    for (int i = 0; i < 16; ++i) {
        float wi = w[i] * inv;
        c0 = fmaf(wi, k0[i], c0); c1 = fmaf(wi, kp[i], c1);
        c2 = fmaf(wi, kq[i], c2); c3 = fmaf(wi, kpq[i], c3);
    }
    C[0] = c0; C[1] = c1; C[2] = c2; C[3] = c3;
}

__global__ void coeff_kernel(const float* __restrict__ sa1, const float* __restrict__ sb1, const float* __restrict__ g1,
                             const float* __restrict__ sa2, const float* __restrict__ sb2, const float* __restrict__ g2,
                             const float* __restrict__ sa3, const float* __restrict__ sb3, const float* __restrict__ g3,
                             const float* __restrict__ sa4, const float* __restrict__ sb4, const float* __restrict__ g4,
                             float* __restrict__ cf) {
    const int t = threadIdx.x;
    if (t < 15) {                 // softmax of sel_a rows
        int r = t;
        if      (r < 8)  softmax_row<9>(sa1 + r * 9,        cf + r * 9);
        else if (r < 12) softmax_row<8>(sa2 + (r - 8) * 8,  cf + 176 + (r - 8) * 8);
        else if (r < 14) softmax_row<4>(sa3 + (r - 12) * 4, cf + 256 + (r - 12) * 4);
        else             softmax_row<2>(sa4,                cf + 280);
    } else if (t >= 16 && t < 31) {   // softmax of sel_b rows
        int r = t - 16;
        if      (r < 8)  softmax_row<9>(sb1 + r * 9,        cf + 72 + r * 9);
        else if (r < 12) softmax_row<8>(sb2 + (r - 8) * 8,  cf + 208 + (r - 8) * 8);
        else if (r < 14) softmax_row<4>(sb3 + (r - 12) * 4, cf + 264 + (r - 12) * 4);
        else             softmax_row<2>(sb4,                cf + 282);
    } else if (t >= 32 && t < 47) {   // gate-logit folds
        int r = t - 32;
        if      (r < 8)  gate_fold(g1 + r * 16,        cf + 144 + r * 4);
        else if (r < 12) gate_fold(g2 + (r - 8) * 16,  cf + 240 + (r - 8) * 4);
        else if (r < 14) gate_fold(g3 + (r - 12) * 16, cf + 272 + (r - 12) * 4);
        else             gate_fold(g4,                 cf + 284);
    }
}

__global__ __launch_bounds__(THREADS, 8) void net_kernel(
        const float* __restrict__ x, const float* __restrict__ cf,
        float* __restrict__ out, int nB) {
    __shared__ __align__(16) float xs[THREADS * 9];   // 9216 B

    const int  tid   = threadIdx.x;
    const long bBase = (long)blockIdx.x * THREADS;    // first sample of block
    const long fBase = bBase * 9;                     // first float of block
    const long totF  = (long)nB * 9;

    // ---- stage block's x-chunk: coalesced float4 loads -> LDS ----
    {
        int nF = (int)((totF - fBase < (long)(THREADS * 9)) ? (totF - fBase)
                                                            : (THREADS * 9));
        int n4 = nF >> 2;                              // whole float4s
        const float4* __restrict__ x4 = (const float4*)(x + fBase); // 9216B-aligned
        #pragma unroll
        for (int k = 0; k < 3; ++k) {                  // 576 = 2*256 + 64
            int idx = tid + k * THREADS;
            if (idx < n4) *(float4*)(xs + idx * 4) = x4[idx];
        }
        for (int i = (n4 << 2) + tid; i < nF; i += THREADS)  // ragged tail
            xs[i] = x[fBase + i];
    }
    __syncthreads();

    const long b = bBase + tid;
    if (b >= nB) return;

    // ---- per-thread sample; coeffs are SGPR (uniform s_load) operands ----
    float v[9];
    #pragma unroll
    for (int i = 0; i < 9; ++i) v[i] = xs[tid * 9 + i];

    // Layer 1: 9 -> 8
    float h1[8];
    #pragma unroll
    for (int j = 0; j < 8; ++j) {
        float p = 0.f, q = 0.f;
        #pragma unroll
        for (int i = 0; i < 9; ++i) {
            p = fmaf(v[i], cf[     j * 9 + i], p);
            q = fmaf(v[i], cf[72 + j * 9 + i], q);
        }
        h1[j] = fmaf(cf[144 + j*4 + 3], p * q,
                fmaf(cf[144 + j*4 + 2], q,
                fmaf(cf[144 + j*4 + 1], p, cf[144 + j*4 + 0])));
    }
    // Layer 2: 8 -> 4
    float h2[4];
    #pragma unroll
    for (int j = 0; j < 4; ++j) {
        float p = 0.f, q = 0.f;
        #pragma unroll
        for (int i = 0; i < 8; ++i) {
            p = fmaf(h1[i], cf[176 + j * 8 + i], p);
            q = fmaf(h1[i], cf[208 + j * 8 + i], q);
        }
        h2[j] = fmaf(cf[240 + j*4 + 3], p * q,
                fmaf(cf[240 + j*4 + 2], q,
                fmaf(cf[240 + j*4 + 1], p, cf[240 + j*4 + 0])));
    }
    // Layer 3: 4 -> 2
    float h3[2];
    #pragma unroll
    for (int j = 0; j < 2; ++j) {
        float p = 0.f, q = 0.f;
        #pragma unroll
        for (int i = 0; i < 4; ++i) {
            p = fmaf(h2[i], cf[256 + j * 4 + i], p);
            q = fmaf(h2[i], cf[264 + j * 4 + i], q);
        }
        h3[j] = fmaf(cf[272 + j*4 + 3], p * q,
                fmaf(cf[272 + j*4 + 2], q,
                fmaf(cf[272 + j*4 + 1], p, cf[272 + j*4 + 0])));
    }
    // Layer 4: 2 -> 1
    {
        float p = fmaf(h3[0], cf[280], h3[1] * cf[281]);
        float q = fmaf(h3[0], cf[282], h3[1] * cf[283]);
        out[b] = fmaf(cf[287], p * q,
                 fmaf(cf[286], q,
                 fmaf(cf[285], p, cf[284])));
    }
}

extern "C" void kernel_launch(void* const* d_in, const int* in_sizes, int n_in,
                              void* d_out, int out_size, void* d_ws, size_t ws_size,
                              hipStream_t stream) {
    const float* x   = (const float*)d_in[0];
    const float* sa1 = (const float*)d_in[1];
    const float* sb1 = (const float*)d_in[2];
    const float* g1  = (const float*)d_in[3];
    const float* sa2 = (const float*)d_in[4];
    const float* sb2 = (const float*)d_in[5];
    const float* g2  = (const float*)d_in[6];
    const float* sa3 = (const float*)d_in[7];
    const float* sb3 = (const float*)d_in[8];
    const float* g3  = (const float*)d_in[9];
    const float* sa4 = (const float*)d_in[10];
    const float* sb4 = (const float*)d_in[11];
    const float* g4  = (const float*)d_in[12];
    float* cf = (float*)d_ws;                 // 288 floats (ws poison is unconditional -> free)
    const int nB = in_sizes[0] / 9;

    coeff_kernel<<<1, 64, 0, stream>>>(sa1, sb1, g1, sa2, sb2, g2,
                                       sa3, sb3, g3, sa4, sb4, g4, cf);
    const int grid = (nB + THREADS - 1) / THREADS;
    net_kernel<<<grid, THREADS, 0, stream>>>(x, cf, (float*)d_out, nB);
}

// Round 5
// 108.282 us; speedup vs baseline: 1.4114x; 1.0175x over previous
//
#include <hip/hip_runtime.h>
#include <math.h>

// ---------------------------------------------------------------------------
// Difflogic network, collapsed form:
//   per neuron: out = c0 + c1*p + c2*q + c3*p*q,  p = A·x, q = B·x
//   A,B = softmax(sel), (c0..c3) = softmax(gate_logits) · gate-coef table
//
// R12 -> R13: halve the VALU stream with packed fp32 (v_pk_fma_f32).
// Evidence: R12 net ~19us vs 6.6us HBM floor / 4us VALU floor; R8 (SPT=4)
// and R12 (SPT=1) both land at K~20-25us -> per-thread instruction count is
// the common bottleneck term. CDNA has VOP3P v_pk_fma_f32/v_pk_mul_f32:
// process 2 consecutive samples per thread with ext_vector float2 math
// (__builtin_elementwise_fma) -> ~2x fewer VALU insts, waves halve to 8192.
// Keep R12's proven-spill-free skeleton:
//   - two kernels: coeff <<<1,64>>> -> d_ws (ws poison is unconditional,
//     so using d_ws is free); cf read via uniform s_load -> SGPR operands.
//   - block stages 512 samples (4608 floats, 18432B LDS) via float4;
//     LDS read stride 18 (4 lanes/bank ~ 1.6x, negligible).
//   - launch_bounds(256,8): 64-VGPR budget; packed body live-set ~50 VGPR.
// Tripwire: WRITE_SIZE >> 5MB means spill -> revert to scalar SPT=1.
//
// ws layout (floats):
//   A1:   0 (72)   B1:  72 (72)   C1: 144 (32)
//   A2: 176 (32)   B2: 208 (32)   C2: 240 (16)
//   A3: 256 ( 8)   B3: 264 ( 8)   C3: 272 ( 8)
//   A4: 280 ( 2)   B4: 282 ( 2)   C4: 284 ( 4)   total 288 floats = 1152 B
// ---------------------------------------------------------------------------

#define THREADS 256
#define SPT 2                              // samples per thread (packed)
#define B_PER_BLOCK (THREADS * SPT)        // 512 samples
#define F_PER_BLOCK (B_PER_BLOCK * 9)      // 4608 floats = 18432 B

typedef float v2f __attribute__((ext_vector_type(2)));

static __device__ __forceinline__ v2f sp(float s) { v2f r; r.x = s; r.y = s; return r; }
static __device__ __forceinline__ v2f pfma(v2f a, v2f b, v2f c) {
    return __builtin_elementwise_fma(a, b, c);
}

template <int D>
__device__ __forceinline__ void softmax_row(const float* __restrict__ src,
                                            float* __restrict__ dst) {
    float e[D];
    float m = src[0];
    #pragma unroll
    for (int i = 1; i < D; ++i) m = fmaxf(m, src[i]);
    float s = 0.f;
    #pragma unroll
    for (int i = 0; i < D; ++i) { e[i] = __expf(src[i] - m); s += e[i]; }
    float inv = 1.f / s;
    #pragma unroll
    for (int i = 0; i < D; ++i) dst[i] = e[i] * inv;
}

__device__ __forceinline__ void gate_fold(const float* __restrict__ g,
                                          float* __restrict__ C) {
    const float k0[16]  = {0,0,0,0, 0,0,0,0, 1, 1, 1, 1, 1, 1, 1, 1};
    const float kp[16]  = {0,0,1,1, 0,0,1,1,-1,-1, 0, 0,-1,-1, 0, 0};
    const float kq[16]  = {0,0,0,0, 1,1,1,1,-1,-1,-1,-1, 0, 0, 0, 0};
    const float kpq[16] = {0,1,-1,0,-1,0,-2,-1, 1, 2, 0, 1, 0, 1,-1, 0};
    float w[16];
    float m = g[0];
    #pragma unroll
    for (int i = 1; i < 16; ++i) m = fmaxf(m, g[i]);
    float s = 0.f;
    #pragma unroll
    for (int i = 0; i < 16; ++i) { w[i] = __expf(g[i] - m); s += w[i]; }
    float inv = 1.f / s;
    float c0 = 0, c1 = 0, c2 = 0, c3 = 0;
    #pragma unroll
    for (int i = 0; i < 16; ++i) {
        float wi = w[i] * inv;
        c0 = fmaf(wi, k0[i], c0); c1 = fmaf(wi, kp[i], c1);
        c2 = fmaf(wi, kq[i], c2); c3 = fmaf(wi, kpq[i], c3);
    }
    C[0] = c0; C[1] = c1; C[2] = c2; C[3] = c3;
}

__global__ void coeff_kernel(const float* __restrict__ sa1, const float* __restrict__ sb1, const float* __restrict__ g1,
                             const float* __restrict__ sa2, const float* __restrict__ sb2, const float* __restrict__ g2,
                             const float* __restrict__ sa3, const float* __restrict__ sb3, const float* __restrict__ g3,
                             const float* __restrict__ sa4, const float* __restrict__ sb4, const float* __restrict__ g4,
                             float* __restrict__ cf) {
    const int t = threadIdx.x;
    if (t < 15) {                 // softmax of sel_a rows
        int r = t;
        if      (r < 8)  softmax_row<9>(sa1 + r * 9,        cf + r * 9);
        else if (r < 12) softmax_row<8>(sa2 + (r - 8) * 8,  cf + 176 + (r - 8) * 8);
        else if (r < 14) softmax_row<4>(sa3 + (r - 12) * 4, cf + 256 + (r - 12) * 4);
        else             softmax_row<2>(sa4,                cf + 280);
    } else if (t >= 16 && t < 31) {   // softmax of sel_b rows
        int r = t - 16;
        if      (r < 8)  softmax_row<9>(sb1 + r * 9,        cf + 72 + r * 9);
        else if (r < 12) softmax_row<8>(sb2 + (r - 8) * 8,  cf + 208 + (r - 8) * 8);
        else if (r < 14) softmax_row<4>(sb3 + (r - 12) * 4, cf + 264 + (r - 12) * 4);
        else             softmax_row<2>(sb4,                cf + 282);
    } else if (t >= 32 && t < 47) {   // gate-logit folds
        int r = t - 32;
        if      (r < 8)  gate_fold(g1 + r * 16,        cf + 144 + r * 4);
        else if (r < 12) gate_fold(g2 + (r - 8) * 16,  cf + 240 + (r - 8) * 4);
        else if (r < 14) gate_fold(g3 + (r - 12) * 16, cf + 272 + (r - 12) * 4);
        else             gate_fold(g4,                 cf + 284);
    }
}

__global__ __launch_bounds__(THREADS, 8) void net_kernel(
        const float* __restrict__ x, const float* __restrict__ cf,
        float* __restrict__ out, int nB) {
    __shared__ __align__(16) float xs[F_PER_BLOCK];   // 18432 B

    const int  tid   = threadIdx.x;
    const long bBase = (long)blockIdx.x * B_PER_BLOCK;  // first sample of block
    const long fBase = bBase * 9;                       // first float (16B-aligned: 4608*4B)
    const long totF  = (long)nB * 9;

    // ---- stage block's x-chunk: coalesced float4 loads -> LDS ----
    {
        int nF = (int)((totF - fBase < (long)F_PER_BLOCK) ? (totF - fBase)
                                                          : (long)F_PER_BLOCK);
        int n4 = nF >> 2;                               // whole float4s (1152 full)
        const float4* __restrict__ x4 = (const float4*)(x + fBase);
        #pragma unroll
        for (int k = 0; k < 5; ++k) {                   // 1152 = 4*256 + 128
            int idx = tid + k * THREADS;
            if (idx < n4) *(float4*)(xs + idx * 4) = x4[idx];
        }
        for (int i = (n4 << 2) + tid; i < nF; i += THREADS)  // ragged tail
            xs[i] = x[fBase + i];
    }
    __syncthreads();

    const long b0 = bBase + (long)tid * SPT;            // first of the pair
    if (b0 >= nB) return;

    // ---- pack 2 consecutive samples into v2f lanes ----
    const int t18 = tid * 18;
    v2f v[9];
    #pragma unroll
    for (int i = 0; i < 9; ++i) {
        v[i].x = xs[t18 + i];
        v[i].y = xs[t18 + 9 + i];   // garbage if b0+1>=nB; never stored
    }

    // ---- Layer 1: 9 -> 8 (packed; coeffs = SGPR splat) ----
    v2f h1[8];
    #pragma unroll
    for (int j = 0; j < 8; ++j) {
        v2f p = sp(0.f), q = sp(0.f);
        #pragma unroll
        for (int i = 0; i < 9; ++i) {
            p = pfma(v[i], sp(cf[     j * 9 + i]), p);
            q = pfma(v[i], sp(cf[72 + j * 9 + i]), q);
        }
        h1[j] = pfma(sp(cf[144 + j*4 + 3]), p * q,
                pfma(sp(cf[144 + j*4 + 2]), q,
                pfma(sp(cf[144 + j*4 + 1]), p, sp(cf[144 + j*4 + 0]))));
    }
    // ---- Layer 2: 8 -> 4 ----
    v2f h2[4];
    #pragma unroll
    for (int j = 0; j < 4; ++j) {
        v2f p = sp(0.f), q = sp(0.f);
        #pragma unroll
        for (int i = 0; i < 8; ++i) {
            p = pfma(h1[i], sp(cf[176 + j * 8 + i]), p);
            q = pfma(h1[i], sp(cf[208 + j * 8 + i]), q);
        }
        h2[j] = pfma(sp(cf[240 + j*4 + 3]), p * q,
                pfma(sp(cf[240 + j*4 + 2]), q,
                pfma(sp(cf[240 + j*4 + 1]), p, sp(cf[240 + j*4 + 0]))));
    }
    // ---- Layer 3: 4 -> 2 ----
    v2f h3[2];
    #pragma unroll
    for (int j = 0; j < 2; ++j) {
        v2f p = sp(0.f), q = sp(0.f);
        #pragma unroll
        for (int i = 0; i < 4; ++i) {
            p = pfma(h2[i], sp(cf[256 + j * 4 + i]), p);
            q = pfma(h2[i], sp(cf[264 + j * 4 + i]), q);
        }
        h3[j] = pfma(sp(cf[272 + j*4 + 3]), p * q,
                pfma(sp(cf[272 + j*4 + 2]), q,
                pfma(sp(cf[272 + j*4 + 1]), p, sp(cf[272 + j*4 + 0]))));
    }
    // ---- Layer 4: 2 -> 1 ----
    v2f p = pfma(h3[0], sp(cf[280]), h3[1] * sp(cf[281]));
    v2f q = pfma(h3[0], sp(cf[282]), h3[1] * sp(cf[283]));
    v2f o = pfma(sp(cf[287]), p * q,
            pfma(sp(cf[286]), q,
            pfma(sp(cf[285]), p, sp(cf[284]))));

    if (b0 + 1 < nB) {
        __builtin_memcpy(&out[b0], &o, 8);   // dwordx2, wave-contiguous
    } else {
        out[b0] = o.x;
    }
}

extern "C" void kernel_launch(void* const* d_in, const int* in_sizes, int n_in,
                              void* d_out, int out_size, void* d_ws, size_t ws_size,
                              hipStream_t stream) {
    const float* x   = (const float*)d_in[0];
    const float* sa1 = (const float*)d_in[1];
    const float* sb1 = (const float*)d_in[2];
    const float* g1  = (const float*)d_in[3];
    const float* sa2 = (const float*)d_in[4];
    const float* sb2 = (const float*)d_in[5];
    const float* g2  = (const float*)d_in[6];
    const float* sa3 = (const float*)d_in[7];
    const float* sb3 = (const float*)d_in[8];
    const float* g3  = (const float*)d_in[9];
    const float* sa4 = (const float*)d_in[10];
    const float* sb4 = (const float*)d_in[11];
    const float* g4  = (const float*)d_in[12];
    float* cf = (float*)d_ws;                 // 288 floats (ws poison is unconditional -> free)
    const int nB = in_sizes[0] / 9;

    coeff_kernel<<<1, 64, 0, stream>>>(sa1, sb1, g1, sa2, sb2, g2,
                                       sa3, sb3, g3, sa4, sb4, g4, cf);
    const int grid = (nB + B_PER_BLOCK - 1) / B_PER_BLOCK;
    net_kernel<<<grid, THREADS, 0, stream>>>(x, cf, (float*)d_out, nB);
}

// Round 6
// 106.409 us; speedup vs baseline: 1.4362x; 1.0176x over previous
//
#include <hip/hip_runtime.h>
#include <math.h>

// ---------------------------------------------------------------------------
// Difflogic network, collapsed form:
//   per neuron: out = c0 + c1*p + c2*q + c3*p*q,  p = A·x, q = B·x
//   A,B = softmax(sel), (c0..c3) = softmax(gate_logits) · gate-coef table
//
// R13 -> R14: delete LDS staging; direct global dwordx2 loads + register
// transpose. Evidence: packed math (R13) removed ~half the VALU stream but
// only gained 1.9us -> net (~20us for 41.9MB = 2.1 TB/s) is NOT VALU-bound;
// remaining in-kernel suspects are the staging path (LDS writes + barrier +
// stride-18 reads). At SPT=2 a thread's 18 floats are contiguous and
// 8B-aligned -> 9x global_load_dwordx2, shuffle to {s0[i],s1[i]} pairs in
// registers (compile-time). Zero LDS, no barrier, live set ~45 VGPR.
// Fusion re-evaluated and rejected: fused cf would need ~84 uniform
// ds_read_b128/thread on the per-CU LDS pipe vs the current FREE SMEM/SGPR
// path (uniform cf pointer + constant offsets -> s_load -> SGPR operands).
// Tripwire: WRITE_SIZE >> 5MB = spill -> revert to R13.
//
// ws layout (floats):
//   A1:   0 (72)   B1:  72 (72)   C1: 144 (32)
//   A2: 176 (32)   B2: 208 (32)   C2: 240 (16)
//   A3: 256 ( 8)   B3: 264 ( 8)   C3: 272 ( 8)
//   A4: 280 ( 2)   B4: 282 ( 2)   C4: 284 ( 4)   total 288 floats = 1152 B
// ---------------------------------------------------------------------------

#define THREADS 256
#define SPT 2                              // samples per thread (packed)
#define B_PER_BLOCK (THREADS * SPT)        // 512 samples

typedef float v2f __attribute__((ext_vector_type(2)));

static __device__ __forceinline__ v2f sp(float s) { v2f r; r.x = s; r.y = s; return r; }
static __device__ __forceinline__ v2f pfma(v2f a, v2f b, v2f c) {
    return __builtin_elementwise_fma(a, b, c);
}

template <int D>
__device__ __forceinline__ void softmax_row(const float* __restrict__ src,
                                            float* __restrict__ dst) {
    float e[D];
    float m = src[0];
    #pragma unroll
    for (int i = 1; i < D; ++i) m = fmaxf(m, src[i]);
    float s = 0.f;
    #pragma unroll
    for (int i = 0; i < D; ++i) { e[i] = __expf(src[i] - m); s += e[i]; }
    float inv = 1.f / s;
    #pragma unroll
    for (int i = 0; i < D; ++i) dst[i] = e[i] * inv;
}

__device__ __forceinline__ void gate_fold(const float* __restrict__ g,
                                          float* __restrict__ C) {
    const float k0[16]  = {0,0,0,0, 0,0,0,0, 1, 1, 1, 1, 1, 1, 1, 1};
    const float kp[16]  = {0,0,1,1, 0,0,1,1,-1,-1, 0, 0,-1,-1, 0, 0};
    const float kq[16]  = {0,0,0,0, 1,1,1,1,-1,-1,-1,-1, 0, 0, 0, 0};
    const float kpq[16] = {0,1,-1,0,-1,0,-2,-1, 1, 2, 0, 1, 0, 1,-1, 0};
    float w[16];
    float m = g[0];
    #pragma unroll
    for (int i = 1; i < 16; ++i) m = fmaxf(m, g[i]);
    float s = 0.f;
    #pragma unroll
    for (int i = 0; i < 16; ++i) { w[i] = __expf(g[i] - m); s += w[i]; }
    float inv = 1.f / s;
    float c0 = 0, c1 = 0, c2 = 0, c3 = 0;
    #pragma unroll
    for (int i = 0; i < 16; ++i) {
        float wi = w[i] * inv;
        c0 = fmaf(wi, k0[i], c0); c1 = fmaf(wi, kp[i], c1);
        c2 = fmaf(wi, kq[i], c2); c3 = fmaf(wi, kpq[i], c3);
    }
    C[0] = c0; C[1] = c1; C[2] = c2; C[3] = c3;
}

__global__ void coeff_kernel(const float* __restrict__ sa1, const float* __restrict__ sb1, const float* __restrict__ g1,
                             const float* __restrict__ sa2, const float* __restrict__ sb2, const float* __restrict__ g2,
                             const float* __restrict__ sa3, const float* __restrict__ sb3, const float* __restrict__ g3,
                             const float* __restrict__ sa4, const float* __restrict__ sb4, const float* __restrict__ g4,
                             float* __restrict__ cf) {
    const int t = threadIdx.x;
    if (t < 15) {                 // softmax of sel_a rows
        int r = t;
        if      (r < 8)  softmax_row<9>(sa1 + r * 9,        cf + r * 9);
        else if (r < 12) softmax_row<8>(sa2 + (r - 8) * 8,  cf + 176 + (r - 8) * 8);
        else if (r < 14) softmax_row<4>(sa3 + (r - 12) * 4, cf + 256 + (r - 12) * 4);
        else             softmax_row<2>(sa4,                cf + 280);
    } else if (t >= 16 && t < 31) {   // softmax of sel_b rows
        int r = t - 16;
        if      (r < 8)  softmax_row<9>(sb1 + r * 9,        cf + 72 + r * 9);
        else if (r < 12) softmax_row<8>(sb2 + (r - 8) * 8,  cf + 208 + (r - 8) * 8);
        else if (r < 14) softmax_row<4>(sb3 + (r - 12) * 4, cf + 264 + (r - 12) * 4);
        else             softmax_row<2>(sb4,                cf + 282);
    } else if (t >= 32 && t < 47) {   // gate-logit folds
        int r = t - 32;
        if      (r < 8)  gate_fold(g1 + r * 16,        cf + 144 + r * 4);
        else if (r < 12) gate_fold(g2 + (r - 8) * 16,  cf + 240 + (r - 8) * 4);
        else if (r < 14) gate_fold(g3 + (r - 12) * 16, cf + 272 + (r - 12) * 4);
        else             gate_fold(g4,                 cf + 284);
    }
}

__global__ __launch_bounds__(THREADS, 8) void net_kernel(
        const float* __restrict__ x, const float* __restrict__ cf,
        float* __restrict__ out, int nB) {
    const long b0 = ((long)blockIdx.x * THREADS + threadIdx.x) * SPT;
    if (b0 >= nB) return;

    // ---- load 2 consecutive samples = 18 contiguous floats, 8B-aligned:
    //      9x global_load_dwordx2; transpose to {s0[i],s1[i]} in registers
    //      (all indices compile-time -> pure register selects). ----
    v2f v[9];
    if (b0 + 1 < nB) {
        const v2f* __restrict__ xp = (const v2f*)(x + b0 * 9);
        v2f r[9];
        #pragma unroll
        for (int i = 0; i < 9; ++i) r[i] = xp[i];
        v[0].x = r[0].x; v[0].y = r[4].y;
        v[1].x = r[0].y; v[1].y = r[5].x;
        v[2].x = r[1].x; v[2].y = r[5].y;
        v[3].x = r[1].y; v[3].y = r[6].x;
        v[4].x = r[2].x; v[4].y = r[6].y;
        v[5].x = r[2].y; v[5].y = r[7].x;
        v[6].x = r[3].x; v[6].y = r[7].y;
        v[7].x = r[3].y; v[7].y = r[8].x;
        v[8].x = r[4].x; v[8].y = r[8].y;
    } else {                                   // last lone sample
        #pragma unroll
        for (int i = 0; i < 9; ++i) { float t = x[b0 * 9 + i]; v[i].x = t; v[i].y = t; }
    }

    // ---- Layer 1: 9 -> 8 (packed; coeffs = SGPR via uniform s_load) ----
    v2f h1[8];
    #pragma unroll
    for (int j = 0; j < 8; ++j) {
        v2f p = sp(0.f), q = sp(0.f);
        #pragma unroll
        for (int i = 0; i < 9; ++i) {
            p = pfma(v[i], sp(cf[     j * 9 + i]), p);
            q = pfma(v[i], sp(cf[72 + j * 9 + i]), q);
        }
        h1[j] = pfma(sp(cf[144 + j*4 + 3]), p * q,
                pfma(sp(cf[144 + j*4 + 2]), q,
                pfma(sp(cf[144 + j*4 + 1]), p, sp(cf[144 + j*4 + 0]))));
    }
    // ---- Layer 2: 8 -> 4 ----
    v2f h2[4];
    #pragma unroll
    for (int j = 0; j < 4; ++j) {
        v2f p = sp(0.f), q = sp(0.f);
        #pragma unroll
        for (int i = 0; i < 8; ++i) {
            p = pfma(h1[i], sp(cf[176 + j * 8 + i]), p);
            q = pfma(h1[i], sp(cf[208 + j * 8 + i]), q);
        }
        h2[j] = pfma(sp(cf[240 + j*4 + 3]), p * q,
                pfma(sp(cf[240 + j*4 + 2]), q,
                pfma(sp(cf[240 + j*4 + 1]), p, sp(cf[240 + j*4 + 0]))));
    }
    // ---- Layer 3: 4 -> 2 ----
    v2f h3[2];
    #pragma unroll
    for (int j = 0; j < 2; ++j) {
        v2f p = sp(0.f), q = sp(0.f);
        #pragma unroll
        for (int i = 0; i < 4; ++i) {
            p = pfma(h2[i], sp(cf[256 + j * 4 + i]), p);
            q = pfma(h2[i], sp(cf[264 + j * 4 + i]), q);
        }
        h3[j] = pfma(sp(cf[272 + j*4 + 3]), p * q,
                pfma(sp(cf[272 + j*4 + 2]), q,
                pfma(sp(cf[272 + j*4 + 1]), p, sp(cf[272 + j*4 + 0]))));
    }
    // ---- Layer 4: 2 -> 1 ----
    v2f p = pfma(h3[0], sp(cf[280]), h3[1] * sp(cf[281]));
    v2f q = pfma(h3[0], sp(cf[282]), h3[1] * sp(cf[283]));
    v2f o = pfma(sp(cf[287]), p * q,
            pfma(sp(cf[286]), q,
            pfma(sp(cf[285]), p, sp(cf[284]))));

    if (b0 + 1 < nB) {
        *(v2f*)(out + b0) = o;                 // dwordx2, wave-contiguous
    } else {
        out[b0] = o.x;
    }
}

extern "C" void kernel_launch(void* const* d_in, const int* in_sizes, int n_in,
                              void* d_out, int out_size, void* d_ws, size_t ws_size,
                              hipStream_t stream) {
    const float* x   = (const float*)d_in[0];
    const float* sa1 = (const float*)d_in[1];
    const float* sb1 = (const float*)d_in[2];
    const float* g1  = (const float*)d_in[3];
    const float* sa2 = (const float*)d_in[4];
    const float* sb2 = (const float*)d_in[5];
    const float* g2  = (const float*)d_in[6];
    const float* sa3 = (const float*)d_in[7];
    const float* sb3 = (const float*)d_in[8];
    const float* g3  = (const float*)d_in[9];
    const float* sa4 = (const float*)d_in[10];
    const float* sb4 = (const float*)d_in[11];
    const float* g4  = (const float*)d_in[12];
    float* cf = (float*)d_ws;                 // 288 floats (ws poison is unconditional -> free)
    const int nB = in_sizes[0] / 9;

    coeff_kernel<<<1, 64, 0, stream>>>(sa1, sb1, g1, sa2, sb2, g2,
                                       sa3, sb3, g3, sa4, sb4, g4, cf);
    const int grid = (nB + B_PER_BLOCK - 1) / B_PER_BLOCK;
    net_kernel<<<grid, THREADS, 0, stream>>>(x, cf, (float*)d_out, nB);
}